// Round 11
// baseline (175.129 us; speedup 1.0000x reference)
//
#include <hip/hip_runtime.h>

#define N_NODES 50000
#define DIM 256
#define NEG 0.2f
#define LN_EPS 1e-5f
#define SCAT_BLOCKS 2048

typedef __attribute__((ext_vector_type(8))) short short8;   // 8 x bf16 (4 VGPRs)
typedef __attribute__((ext_vector_type(4))) float f32x4;    // MFMA accumulator

__device__ __forceinline__ unsigned short f2bf(float x) {   // RNE fp32 -> bf16
    unsigned int u = __builtin_bit_cast(unsigned int, x);
    u += 0x7fffu + ((u >> 16) & 1u);
    return (unsigned short)(u >> 16);
}

__device__ __forceinline__ short8 cvt_bfrag(float4 a4, float4 b4) {
    short8 r;
    r[0] = (short)f2bf(a4.x); r[1] = (short)f2bf(a4.y);
    r[2] = (short)f2bf(a4.z); r[3] = (short)f2bf(a4.w);
    r[4] = (short)f2bf(b4.x); r[5] = (short)f2bf(b4.y);
    r[6] = (short)f2bf(b4.z); r[7] = (short)f2bf(b4.w);
    return r;
}

// ---------- prep: Wr -> fragment-ordered bf16 WrF  +  relation byte-mask scatter ----------
// WrF layout (proven r2-r10): frag f = kk*16+mt (kk = 32-wide k-step, mt = 16-col m-tile),
// 64 lanes x 16B: WrF[(f*64+lane)*8 + j] = bf16(Wr[kk*32 + (lane>>4)*8 + j][mt*16 + (lane&15)])
__global__ __launch_bounds__(256) void prep(
    const float* __restrict__ Wr, unsigned short* __restrict__ WrF,
    const int* __restrict__ d0, const int* __restrict__ d1, const int* __restrict__ d2,
    int E, unsigned char* __restrict__ mask)
{
    if (blockIdx.x < 32) {                       // 32*256 = 8192 = 128 frags x 64 lanes
        const int o    = blockIdx.x * 256 + threadIdx.x;
        const int lane = o & 63;
        const int frag = o >> 6;                 // kk*16 + mt
        const int mt = frag & 15, kk = frag >> 4;
        const int ln = lane & 15, quad = lane >> 4;
        const float* src = Wr + (size_t)(kk * 32 + quad * 8) * DIM + mt * 16 + ln;
        short8 v;
        #pragma unroll
        for (int j = 0; j < 8; ++j) v[j] = (short)f2bf(src[(size_t)j * DIM]);
        *(short8*)(WrF + (size_t)o * 8) = v;
    } else {
        // racing byte-stores of the same value are benign; memset zeroed the mask
        const int total = 3 * E;
        for (int i = (blockIdx.x - 32) * 256 + (int)threadIdx.x; i < total;
             i += SCAT_BLOCKS * 256) {
            const int* d; int base, e;
            if (i >= 2 * E)  { d = d2; e = i - 2 * E; base = 2 * N_NODES; }
            else if (i >= E) { d = d1; e = i - E;     base = N_NODES; }
            else             { d = d0; e = i;         base = 0; }
            mask[base + d[e]] = (unsigned char)1;
        }
    }
}

// ---------- fused GEMM: ZERO LDS, ZERO barriers — fully independent waves ----------
// Every r1-r10 variant was a barrier-coupled LDS pipeline at 2 blocks/CU: 4 waves
// serialize on vmcnt(0)-draining __syncthreads, leaving ONE other block per CU to
// hide latency -> the invariant ~42 us. This kernel removes the coupling: W is
// read per-wave straight from L2 (WrF = 128 KB, hot in every XCD L2; fragment
// order makes each A-load a dense coalesced 1 KB/instr — fixing r0's 4x-splatter),
// with an explicit depth-2 rotating prefetch Ab[3][4] (static indices after
// unroll -> registers, ~8 loads in flight). No __shared__, no __syncthreads:
// 12 independent waves/CU (VGPR ~160 under the (256,3) cap) all stream freely.
// Accumulation order (kk ascending per acc[mt]) unchanged -> bit-identical out.
__global__ __launch_bounds__(256, 3) void fused_mfma(
    const float* __restrict__ feat, const unsigned short* __restrict__ WrF,
    const float* __restrict__ br, const float* __restrict__ rel_q,
    const float* __restrict__ rel_k, const float* __restrict__ gamma,
    const float* __restrict__ beta_p, const unsigned char* __restrict__ mask,
    float* __restrict__ out)
{
    const int lane = threadIdx.x & 63;
    const int wave = threadIdx.x >> 6;
    const int ln = lane & 15;      // node within wave / MFMA n
    const int quad = lane >> 4;    // MFMA k-quad & D-row-quad
    int node = blockIdx.x * 64 + wave * 16 + ln;
    const bool valid = node < N_NODES;
    if (!valid) node = N_NODES - 1;              // clamp: loads safe, store guarded

    // mask bytes (epilogue-only; issue first, latency hides under everything)
    const int m0 = (int)mask[node];
    const int m1 = (int)mask[N_NODES + node];
    const int m2 = (int)mask[2 * N_NODES + node];

    // full feat-row prefetch + one-time bf16 conversion (r1-proven); F dies here
    const float* fptr = feat + (size_t)node * DIM + quad * 8;
    float4 F0[8], F1[8];
    #pragma unroll
    for (int kk = 0; kk < 8; ++kk) {
        F0[kk] = *(const float4*)(fptr + kk * 32);
        F1[kk] = *(const float4*)(fptr + kk * 32 + 4);
    }
    short8 bfr[8];
    #pragma unroll
    for (int kk = 0; kk < 8; ++kk) bfr[kk] = cvt_bfrag(F0[kk], F1[kk]);

    f32x4 acc[16];
    #pragma unroll
    for (int mt = 0; mt < 16; ++mt) acc[mt] = (f32x4){0.f, 0.f, 0.f, 0.f};

    // ---- K-loop: 32 groups of 4 frags, depth-2 rotating register prefetch ----
    const char* wptr = (const char*)WrF + lane * 16;     // + frag*1024
    short8 Ab[3][4];                                     // 48 VGPRs, static-indexed
    #pragma unroll
    for (int j = 0; j < 4; ++j) Ab[0][j] = *(const short8*)(wptr + (size_t)(0 + j) * 1024);
    #pragma unroll
    for (int j = 0; j < 4; ++j) Ab[1][j] = *(const short8*)(wptr + (size_t)(4 + j) * 1024);

    #pragma unroll
    for (int g = 0; g < 32; ++g) {               // g = kk*4 + mgroup; all static
        if (g < 30) {
            #pragma unroll
            for (int j = 0; j < 4; ++j)
                Ab[(g + 2) % 3][j] = *(const short8*)(wptr + (size_t)((g + 2) * 4 + j) * 1024);
        }
        const int kk = g >> 2, mb = (g & 3) * 4;
        #pragma unroll
        for (int j = 0; j < 4; ++j)
            acc[mb + j] = __builtin_amdgcn_mfma_f32_16x16x32_bf16(
                Ab[g % 3][j], bfr[kk], acc[mb + j], 0, 0, 0);
    }

    // ---- epilogue: bias, per-head dots, softmax weight, ReLU, LayerNorm (proven) ----
    float qp[4] = {0.f, 0.f, 0.f, 0.f}, kp[4] = {0.f, 0.f, 0.f, 0.f};
    #pragma unroll
    for (int mt = 0; mt < 16; ++mt) {
        const int cbase = mt * 16 + quad * 4;
        const float4 bb = *(const float4*)(br + cbase);
        acc[mt][0] += bb.x; acc[mt][1] += bb.y; acc[mt][2] += bb.z; acc[mt][3] += bb.w;
        const float4 rq = *(const float4*)(rel_q + cbase);
        const float4 rk = *(const float4*)(rel_k + cbase);
        const int h = mt >> 2;
        qp[h] += acc[mt][0] * rq.x + acc[mt][1] * rq.y + acc[mt][2] * rq.z + acc[mt][3] * rq.w;
        kp[h] += acc[mt][0] * rk.x + acc[mt][1] * rk.y + acc[mt][2] * rk.z + acc[mt][3] * rk.w;
    }
    #pragma unroll
    for (int h = 0; h < 4; ++h) {
        qp[h] += __shfl_xor(qp[h], 16); qp[h] += __shfl_xor(qp[h], 32);
        kp[h] += __shfl_xor(kp[h], 16); kp[h] += __shfl_xor(kp[h], 32);
    }

    const int cnt = m0 + m1 + m2;

    float wgt[4];
    #pragma unroll
    for (int h = 0; h < 4; ++h) {
        const float q = qp[h];
        const float qk = q + kp[h];
        const float a = q  > 0.f ? q  : NEG * q;    // inactive-relation logit
        const float b = qk > 0.f ? qk : NEG * qk;   // active/self logit
        const float mx = fmaxf(a, b);
        const float eb = (float)(cnt + 1) * __expf(b - mx);
        const float ea = (float)(3 - cnt) * __expf(a - mx);
        wgt[h] = eb / (eb + ea);
    }

    float sum = 0.f, ssq = 0.f;
    #pragma unroll
    for (int mt = 0; mt < 16; ++mt) {
        const float w = wgt[mt >> 2];
        #pragma unroll
        for (int r = 0; r < 4; ++r) {
            float v = fmaxf(acc[mt][r] * w, 0.f);   // ReLU
            acc[mt][r] = v;
            sum += v; ssq += v * v;
        }
    }
    sum += __shfl_xor(sum, 16); sum += __shfl_xor(sum, 32);
    ssq += __shfl_xor(ssq, 16); ssq += __shfl_xor(ssq, 32);
    const float mu = sum * (1.f / 256.f);
    const float var = ssq * (1.f / 256.f) - mu * mu;
    const float rstd = rsqrtf(var + LN_EPS);

    if (valid) {
        // direct store: per instruction, 4 quads of each node cover one full 64 B
        // line (16 lines/instr, all fully written) — line-dense, r8/r9-verified
        float* optr = out + (size_t)node * DIM;
        #pragma unroll
        for (int mt = 0; mt < 16; ++mt) {
            const int cbase = mt * 16 + quad * 4;
            const float4 g = *(const float4*)(gamma + cbase);
            const float4 b = *(const float4*)(beta_p + cbase);
            float4 r;
            r.x = (acc[mt][0] - mu) * rstd * g.x + b.x;
            r.y = (acc[mt][1] - mu) * rstd * g.y + b.y;
            r.z = (acc[mt][2] - mu) * rstd * g.z + b.z;
            r.w = (acc[mt][3] - mu) * rstd * g.w + b.w;
            *(float4*)(optr + cbase) = r;
        }
    }
}

extern "C" void kernel_launch(void* const* d_in, const int* in_sizes, int n_in,
                              void* d_out, int out_size, void* d_ws, size_t ws_size,
                              hipStream_t stream) {
    const float* feat  = (const float*)d_in[0];
    // d_in[1] Wl, d_in[2] bl, d_in[5] attn_l, d_in[6] attn_r, edge_src_*: dead code
    const float* Wr    = (const float*)d_in[3];
    const float* br    = (const float*)d_in[4];
    const float* rel_q = (const float*)d_in[7];
    const float* rel_k = (const float*)d_in[8];
    const float* gamma = (const float*)d_in[9];
    const float* beta  = (const float*)d_in[10];
    const int* dst0 = (const int*)d_in[12];
    const int* dst1 = (const int*)d_in[14];
    const int* dst2 = (const int*)d_in[16];
    const int E = in_sizes[12];

    // d_ws layout: WrF fragment-ordered bf16 (131072 B) | byte mask (150016 B)
    unsigned short* WrF = (unsigned short*)d_ws;
    unsigned char* mask = (unsigned char*)d_ws + DIM * DIM * 2;

    hipMemsetAsync(mask, 0, 150016, stream);
    prep<<<32 + SCAT_BLOCKS, 256, 0, stream>>>(Wr, WrF, dst0, dst1, dst2, E, mask);
    fused_mfma<<<(N_NODES + 63) / 64, 256, 0, stream>>>(
        feat, WrF, br, rel_q, rel_k, gamma, beta, mask, (float*)d_out);
}

// Round 12
// 163.545 us; speedup vs baseline: 1.0708x; 1.0708x over previous
//
#include <hip/hip_runtime.h>

#define N_NODES 50000
#define DIM 256
#define NEG 0.2f
#define LN_EPS 1e-5f
#define SCAT_BLOCKS 2048

typedef __attribute__((ext_vector_type(8))) short short8;   // 8 x bf16 (4 VGPRs)
typedef __attribute__((ext_vector_type(4))) float f32x4;    // MFMA accumulator

__device__ __forceinline__ unsigned short f2bf(float x) {   // RNE fp32 -> bf16
    unsigned int u = __builtin_bit_cast(unsigned int, x);
    u += 0x7fffu + ((u >> 16) & 1u);
    return (unsigned short)(u >> 16);
}

__device__ __forceinline__ void load_lds16(const void* g, void* l) {
    // async global->LDS, 16B/lane, dest = wave-uniform base + lane*16 (linear)
    __builtin_amdgcn_global_load_lds((const unsigned int*)g, (unsigned int*)l, 16, 0, 0);
}

__device__ __forceinline__ short8 cvt_bfrag(float4 a4, float4 b4) {
    short8 r;
    r[0] = (short)f2bf(a4.x); r[1] = (short)f2bf(a4.y);
    r[2] = (short)f2bf(a4.z); r[3] = (short)f2bf(a4.w);
    r[4] = (short)f2bf(b4.x); r[5] = (short)f2bf(b4.y);
    r[6] = (short)f2bf(b4.z); r[7] = (short)f2bf(b4.w);
    return r;
}

// ---------- prep: Wr -> fragment-ordered bf16 WrF  +  relation byte-mask scatter ----------
// WrF layout (proven r2-r11): frag f = kk*16+mt (kk = 32-wide k-step, mt = 16-col m-tile),
// 64 lanes x 16B: WrF[(f*64+lane)*8 + j] = bf16(Wr[kk*32 + (lane>>4)*8 + j][mt*16 + (lane&15)])
__global__ __launch_bounds__(256) void prep(
    const float* __restrict__ Wr, unsigned short* __restrict__ WrF,
    const int* __restrict__ d0, const int* __restrict__ d1, const int* __restrict__ d2,
    int E, unsigned char* __restrict__ mask)
{
    if (blockIdx.x < 32) {                       // 32*256 = 8192 = 128 frags x 64 lanes
        const int o    = blockIdx.x * 256 + threadIdx.x;
        const int lane = o & 63;
        const int frag = o >> 6;                 // kk*16 + mt
        const int mt = frag & 15, kk = frag >> 4;
        const int ln = lane & 15, quad = lane >> 4;
        const float* src = Wr + (size_t)(kk * 32 + quad * 8) * DIM + mt * 16 + ln;
        short8 v;
        #pragma unroll
        for (int j = 0; j < 8; ++j) v[j] = (short)f2bf(src[(size_t)j * DIM]);
        *(short8*)(WrF + (size_t)o * 8) = v;
    } else {
        // racing byte-stores of the same value are benign; memset zeroed the mask
        const int total = 3 * E;
        for (int i = (blockIdx.x - 32) * 256 + (int)threadIdx.x; i < total;
             i += SCAT_BLOCKS * 256) {
            const int* d; int base, e;
            if (i >= 2 * E)  { d = d2; e = i - 2 * E; base = 2 * N_NODES; }
            else if (i >= E) { d = d1; e = i - E;     base = N_NODES; }
            else             { d = d0; e = i;         base = 0; }
            mask[base + d[e]] = (unsigned char)1;
        }
    }
}

// ---------- fused GEMM, split-M paired waves: 4 blocks/CU WITHOUT spill ----------
// Block = 4 waves, 32 nodes: waves (2g+h) pair on node-group g (16 nodes), each
// owning 8 m-tiles (h=0: mt 0-7 = heads 0,1; h=1: mt 8-15 = heads 2,3). acc
// halves to 32 regs -> total live ~105 <= the 128-reg cap of bounds(256,4)
// (r4's identical structure needed ~140 and spilled; this is the fix).
// W streams through the r4-proven 2x16KB ping-pong via global_load_lds (immune
// to register caps - r11 lesson: the compiler sinks VGPR prefetch arrays, but
// LDS-DMA holds nothing in VGPRs). One barrier per kstep. Head-aligned split
// means attention weights need NO cross-wave exchange (head h's columns lie
// entirely in one half); only LayerNorm sum/ssq (2 floats) crosses waves via
// 512 B LDS + 1 barrier. qp/kp/wgt/acc bit-identical to r1-r10; only the
// mu/var addition order changes ((Sum0-7)+(Sum8-15) vs Sum0-15), ~1 ulp.
// 33 KB LDS -> 4 blocks/CU -> 16 waves/CU: 2x the r1-r10 occupancy invariant.
__global__ __launch_bounds__(256, 4) void fused_mfma(
    const float* __restrict__ feat, const unsigned short* __restrict__ WrF,
    const float* __restrict__ br, const float* __restrict__ rel_q,
    const float* __restrict__ rel_k, const float* __restrict__ gamma,
    const float* __restrict__ beta_p, const unsigned char* __restrict__ mask,
    float* __restrict__ out)
{
    __shared__ char lds[33280];                  // 2x16KB W ping-pong + 512B ss-xchg
    const int lane = threadIdx.x & 63;
    const int wave = threadIdx.x >> 6;
    const int mhalf = wave & 1;                  // which 8 m-tiles / head pair
    const int ng = wave >> 1;                    // node group within block
    const int ln = lane & 15;      // node within group / MFMA n
    const int quad = lane >> 4;    // MFMA k-quad & D-row-quad
    int node = blockIdx.x * 32 + ng * 16 + ln;
    const bool valid = node < N_NODES;
    if (!valid) node = N_NODES - 1;              // clamp: loads safe, store guarded

    // ---- stage W kstep 0 into buf 0 (4 x 1KB per wave) ----
    {
        const char* g = (const char*)WrF;
        #pragma unroll
        for (int r = 0; r < 4; ++r) {
            const int off = wave * 4096 + r * 1024;      // wave-uniform
            load_lds16(g + off + lane * 16, lds + off);
        }
    }

    // ---- mask bytes (epilogue-only; hide latency now) ----
    const int m0 = (int)mask[node];
    const int m1 = (int)mask[N_NODES + node];
    const int m2 = (int)mask[2 * N_NODES + node];

    // ---- feat row -> bf16 B-fragments, 4 chunks of 2 ksteps (peak F = 16 regs) ----
    const float* fptr = feat + (size_t)node * DIM + quad * 8;
    short8 bfr[8];
    #pragma unroll
    for (int c = 0; c < 4; ++c) {
        float4 F0[2], F1[2];
        #pragma unroll
        for (int k = 0; k < 2; ++k) {
            F0[k] = *(const float4*)(fptr + (c * 2 + k) * 32);
            F1[k] = *(const float4*)(fptr + (c * 2 + k) * 32 + 4);
        }
        #pragma unroll
        for (int k = 0; k < 2; ++k) bfr[c * 2 + k] = cvt_bfrag(F0[k], F1[k]);
    }

    f32x4 acc[8];
    #pragma unroll
    for (int j = 0; j < 8; ++j) acc[j] = (f32x4){0.f, 0.f, 0.f, 0.f};

    __syncthreads();                             // kstep 0 staged (vmcnt drain)

    // ---- K-loop: stage kstep kk+1 || 8 ds_read_b128 + 8 MFMA (own m-half) ----
    #pragma unroll
    for (int kk = 0; kk < 8; ++kk) {
        if (kk < 7) {                            // into the idle half (r4 handshake)
            const char* g = (const char*)WrF + (kk + 1) * 16384;
            char* l = lds + (((kk + 1) & 1) << 14);
            #pragma unroll
            for (int r = 0; r < 4; ++r) {
                const int off = wave * 4096 + r * 1024;
                load_lds16(g + off + lane * 16, l + off);
            }
        }
        const char* wb = lds + ((kk & 1) << 14) + mhalf * 8192 + lane * 16;
        #pragma unroll
        for (int j = 0; j < 8; ++j) {            // static j: acc never runtime-indexed
            const short8 a = *(const short8*)(wb + j * 1024);
            acc[j] = __builtin_amdgcn_mfma_f32_16x16x32_bf16(a, bfr[kk], acc[j], 0, 0, 0);
        }
        if (kk < 7) __syncthreads();             // next buf staged + cur buf free
    }

    // ---- epilogue: bias + per-head dots over OWN 8 m-tiles (own 2 heads complete) ----
    float qp[2] = {0.f, 0.f}, kp[2] = {0.f, 0.f};
    #pragma unroll
    for (int j = 0; j < 8; ++j) {
        const int cbase = (mhalf * 8 + j) * 16 + quad * 4;
        const float4 bb = *(const float4*)(br + cbase);
        acc[j][0] += bb.x; acc[j][1] += bb.y; acc[j][2] += bb.z; acc[j][3] += bb.w;
        const float4 rq = *(const float4*)(rel_q + cbase);
        const float4 rk = *(const float4*)(rel_k + cbase);
        const int hh = j >> 2;                   // local head 0/1
        qp[hh] += acc[j][0] * rq.x + acc[j][1] * rq.y + acc[j][2] * rq.z + acc[j][3] * rq.w;
        kp[hh] += acc[j][0] * rk.x + acc[j][1] * rk.y + acc[j][2] * rk.z + acc[j][3] * rk.w;
    }
    #pragma unroll
    for (int hh = 0; hh < 2; ++hh) {
        qp[hh] += __shfl_xor(qp[hh], 16); qp[hh] += __shfl_xor(qp[hh], 32);
        kp[hh] += __shfl_xor(kp[hh], 16); kp[hh] += __shfl_xor(kp[hh], 32);
    }

    const int cnt = m0 + m1 + m2;

    float wgt[2];                                // weights for own 2 heads only
    #pragma unroll
    for (int hh = 0; hh < 2; ++hh) {
        const float q = qp[hh];
        const float qk = q + kp[hh];
        const float a = q  > 0.f ? q  : NEG * q;    // inactive-relation logit
        const float b = qk > 0.f ? qk : NEG * qk;   // active/self logit
        const float mx = fmaxf(a, b);
        const float eb = (float)(cnt + 1) * __expf(b - mx);
        const float ea = (float)(3 - cnt) * __expf(a - mx);
        wgt[hh] = eb / (eb + ea);
    }

    float sum = 0.f, ssq = 0.f;                  // partial over own half-row
    #pragma unroll
    for (int j = 0; j < 8; ++j) {
        const float w = wgt[j >> 2];
        #pragma unroll
        for (int r = 0; r < 4; ++r) {
            float v = fmaxf(acc[j][r] * w, 0.f);    // ReLU
            acc[j][r] = v;
            sum += v; ssq += v * v;
        }
    }
    sum += __shfl_xor(sum, 16); sum += __shfl_xor(sum, 32);
    ssq += __shfl_xor(ssq, 16); ssq += __shfl_xor(ssq, 32);

    // ---- cross-wave sum/ssq exchange (512 B LDS region, disjoint from W bufs) ----
    float* ss = (float*)(lds + 32768);           // [ (ng*2+mhalf)*16 + ln ] x float2
    if (quad == 0) {
        const int idx = ((ng * 2 + mhalf) * 16 + ln) * 2;
        ss[idx] = sum; ss[idx + 1] = ssq;
    }
    __syncthreads();
    {
        const int pidx = ((ng * 2 + (1 - mhalf)) * 16 + ln) * 2;
        sum += ss[pidx]; ssq += ss[pidx + 1];
    }
    const float mu = sum * (1.f / 256.f);
    const float var = ssq * (1.f / 256.f) - mu * mu;
    const float rstd = rsqrtf(var + LN_EPS);

    if (valid) {
        float* optr = out + (size_t)node * DIM;
        #pragma unroll
        for (int j = 0; j < 8; ++j) {
            const int cbase = (mhalf * 8 + j) * 16 + quad * 4;
            const float4 g = *(const float4*)(gamma + cbase);
            const float4 b = *(const float4*)(beta_p + cbase);
            float4 r;
            r.x = (acc[j][0] - mu) * rstd * g.x + b.x;
            r.y = (acc[j][1] - mu) * rstd * g.y + b.y;
            r.z = (acc[j][2] - mu) * rstd * g.z + b.z;
            r.w = (acc[j][3] - mu) * rstd * g.w + b.w;
            *(float4*)(optr + cbase) = r;
        }
    }
}

extern "C" void kernel_launch(void* const* d_in, const int* in_sizes, int n_in,
                              void* d_out, int out_size, void* d_ws, size_t ws_size,
                              hipStream_t stream) {
    const float* feat  = (const float*)d_in[0];
    // d_in[1] Wl, d_in[2] bl, d_in[5] attn_l, d_in[6] attn_r, edge_src_*: dead code
    const float* Wr    = (const float*)d_in[3];
    const float* br    = (const float*)d_in[4];
    const float* rel_q = (const float*)d_in[7];
    const float* rel_k = (const float*)d_in[8];
    const float* gamma = (const float*)d_in[9];
    const float* beta  = (const float*)d_in[10];
    const int* dst0 = (const int*)d_in[12];
    const int* dst1 = (const int*)d_in[14];
    const int* dst2 = (const int*)d_in[16];
    const int E = in_sizes[12];

    // d_ws layout: WrF fragment-ordered bf16 (131072 B) | byte mask (150016 B)
    unsigned short* WrF = (unsigned short*)d_ws;
    unsigned char* mask = (unsigned char*)d_ws + DIM * DIM * 2;

    hipMemsetAsync(mask, 0, 150016, stream);
    prep<<<32 + SCAT_BLOCKS, 256, 0, stream>>>(Wr, WrF, dst0, dst1, dst2, E, mask);
    fused_mfma<<<(N_NODES + 31) / 32, 256, 0, stream>>>(
        feat, WrF, br, rel_q, rel_k, gamma, beta, mask, (float*)d_out);
}